// Round 2
// baseline (559.529 us; speedup 1.0000x reference)
//
#include <hip/hip_runtime.h>

#define SEQ 512
#define EMB 8
#define NFAC 4

// ws layout (floats):
// [0:64)    wkq[p][e]   folded cross-attn score weights (p = h*4+f), incl. 1/sqrt(Dh)
// [64:72)   csb[p]      folded score bias
// [72:136)  M0[e][e2]   head-0 fold: sum_d w_out[e][0*4+d]*wv[0*4+d][e2]
// [136:200) M1[e][e2]   head-1 fold
// [200:208) B2[e]       qcr bias fold: ca_b_out[e] + sum_hd w_out[e][hd]*bv[hd]
// [208:720) w1[t][k]    MLP layer 1 (16 x 32)
// [720:736) b1[t]
// [736:752) w2[t]
// [752]     b2

// ---------------------------------------------------------------------------
// Precompute (batch-independent): self-attn over Q -> folded score weights,
// plus the ctx->qcr fold matrices, plus a copy of the MLP weights into ws.
// ---------------------------------------------------------------------------
__global__ void precompute_kernel(
    const float* __restrict__ Q,
    const float* __restrict__ sa_w_in, const float* __restrict__ sa_b_in,
    const float* __restrict__ sa_w_out, const float* __restrict__ sa_b_out,
    const float* __restrict__ ca_w_in, const float* __restrict__ ca_b_in,
    const float* __restrict__ ca_w_out, const float* __restrict__ ca_b_out,
    const float* __restrict__ r_w1, const float* __restrict__ r_b1,
    const float* __restrict__ r_w2, const float* __restrict__ r_b2,
    float* __restrict__ ws)
{
    const int tid = threadIdx.x;
    // parallel copy of MLP weights
    for (int k = tid; k < 512; k += 64) ws[208 + k] = r_w1[k];
    if (tid < 16) { ws[720 + tid] = r_b1[tid]; ws[736 + tid] = r_w2[tid]; }
    if (tid != 0) return;
    ws[752] = r_b2[0];

    float qh[4][8], kh[4][8], vh[4][8];
    for (int l = 0; l < 4; ++l)
        for (int j = 0; j < 8; ++j) {
            float aq = sa_b_in[j], ak = sa_b_in[8 + j], av = sa_b_in[16 + j];
            for (int e = 0; e < 8; ++e) {
                float q = Q[l * 8 + e];
                aq += q * sa_w_in[j * 8 + e];
                ak += q * sa_w_in[(8 + j) * 8 + e];
                av += q * sa_w_in[(16 + j) * 8 + e];
            }
            qh[l][j] = aq; kh[l][j] = ak; vh[l][j] = av;
        }
    float ctxf[4][8];
    for (int h = 0; h < 2; ++h)
        for (int l = 0; l < 4; ++l) {
            float sc[4];
            float mx = -1e30f;
            for (int m = 0; m < 4; ++m) {
                float a = 0.f;
                for (int d = 0; d < 4; ++d) a += qh[l][h*4+d] * kh[m][h*4+d];
                sc[m] = 0.5f * a;
                mx = fmaxf(mx, sc[m]);
            }
            float ssum = 0.f;
            for (int m = 0; m < 4; ++m) { sc[m] = __expf(sc[m] - mx); ssum += sc[m]; }
            for (int d = 0; d < 4; ++d) {
                float a = 0.f;
                for (int m = 0; m < 4; ++m) a += sc[m] * vh[m][h*4+d];
                ctxf[l][h*4+d] = a / ssum;
            }
        }
    float Qu[4][8];
    for (int l = 0; l < 4; ++l)
        for (int e2 = 0; e2 < 8; ++e2) {
            float a = sa_b_out[e2];
            for (int e = 0; e < 8; ++e) a += ctxf[l][e] * sa_w_out[e2 * 8 + e];
            Qu[l][e2] = a;
        }
    float qc[4][8];  // cross-attn query heads [f][h*4+d]
    for (int l = 0; l < 4; ++l)
        for (int j = 0; j < 8; ++j) {
            float a = ca_b_in[j];
            for (int e = 0; e < 8; ++e) a += Qu[l][e] * ca_w_in[j * 8 + e];
            qc[l][j] = a;
        }
    // folded score weights: scores[p][s] = wkq[p].x[s] + csb[p], p = h*4+f
    for (int h = 0; h < 2; ++h)
        for (int f = 0; f < 4; ++f) {
            int p = h * 4 + f;
            for (int e = 0; e < 8; ++e) {
                float a = 0.f;
                for (int d = 0; d < 4; ++d) a += qc[f][h*4+d] * ca_w_in[(8 + h*4+d) * 8 + e];
                ws[p * 8 + e] = 0.5f * a;
            }
            float a = 0.f;
            for (int d = 0; d < 4; ++d) a += qc[f][h*4+d] * ca_b_in[8 + h*4+d];
            ws[64 + p] = 0.5f * a;
        }
    // ctx->qcr fold: M_h[e][e2] = sum_d w_out[e][h4+d] * wv[h4+d][e2]
    for (int h = 0; h < 2; ++h)
        for (int e = 0; e < 8; ++e)
            for (int e2 = 0; e2 < 8; ++e2) {
                float a = 0.f;
                for (int d = 0; d < 4; ++d)
                    a += ca_w_out[e*8 + h*4+d] * ca_w_in[(16 + h*4+d)*8 + e2];
                ws[72 + h*64 + e*8 + e2] = a;
            }
    for (int e = 0; e < 8; ++e) {
        float a = ca_b_out[e];
        for (int hd = 0; hd < 8; ++hd) a += ca_w_out[e*8 + hd] * ca_b_in[16 + hd];
        ws[200 + e] = a;
    }
}

// ---------------------------------------------------------------------------
// DPP wave reduction (VALU pipe only — no LDS traffic)
// ---------------------------------------------------------------------------
__device__ __forceinline__ float wave_sum64(float v) {
    v += __int_as_float(__builtin_amdgcn_update_dpp(0, __float_as_int(v), 0x111, 0xf, 0xf, true)); // row_shr:1
    v += __int_as_float(__builtin_amdgcn_update_dpp(0, __float_as_int(v), 0x112, 0xf, 0xf, true)); // row_shr:2
    v += __int_as_float(__builtin_amdgcn_update_dpp(0, __float_as_int(v), 0x114, 0xf, 0xf, true)); // row_shr:4
    v += __int_as_float(__builtin_amdgcn_update_dpp(0, __float_as_int(v), 0x118, 0xf, 0xf, true)); // row_shr:8
    v += __int_as_float(__builtin_amdgcn_update_dpp(0, __float_as_int(v), 0x142, 0xa, 0xf, true)); // bcast15 -> rows 1,3
    v += __int_as_float(__builtin_amdgcn_update_dpp(0, __float_as_int(v), 0x143, 0xc, 0xf, true)); // bcast31 -> rows 2,3
    return v;  // lane 63 holds the full-wave sum
}
__device__ __forceinline__ float row16_sum(float v) {
    v += __int_as_float(__builtin_amdgcn_update_dpp(0, __float_as_int(v), 0x111, 0xf, 0xf, true));
    v += __int_as_float(__builtin_amdgcn_update_dpp(0, __float_as_int(v), 0x112, 0xf, 0xf, true));
    v += __int_as_float(__builtin_amdgcn_update_dpp(0, __float_as_int(v), 0x114, 0xf, 0xf, true));
    v += __int_as_float(__builtin_amdgcn_update_dpp(0, __float_as_int(v), 0x118, 0xf, 0xf, true));
    return v;  // lane 15 of each 16-row holds the row sum
}

__device__ __forceinline__ float uload(const float* p) {  // force wave-uniform -> SGPR
    return __int_as_float(__builtin_amdgcn_readfirstlane(__float_as_int(*p)));
}

// ---------------------------------------------------------------------------
// One wave per batch, 4 waves (4 batches) per block. No barriers, no
// inter-wave communication. x cached in VGPRs across both passes.
// ---------------------------------------------------------------------------
__global__ __launch_bounds__(256, 3) void fused_kernel(
    const float* __restrict__ x, const float* __restrict__ ws,
    float* __restrict__ out, float* __restrict__ sim_out)
{
    const int tid = threadIdx.x;
    const int w = __builtin_amdgcn_readfirstlane(tid >> 6);
    const int lane = tid & 63;
    const int b = blockIdx.x * 4 + w;

    __shared__ float sX[4][72];   // per-wave: X_p[8][8] then S_p[8]
    __shared__ float sQ[4][32];   // per-wave: qcr[f][e]
    __shared__ float sF[4][32];   // per-wave: normalized final_factors

    const float* xb = x + (size_t)b * (SEQ * EMB);

    // ---- load the wave's 16 KB x-slice into registers (fetched once)
    float4 lo[8], hi[8];
    #pragma unroll
    for (int j = 0; j < 8; ++j) {
        const float4* xp = (const float4*)(xb + (size_t)(lane + 64 * j) * EMB);
        lo[j] = xp[0];
        hi[j] = xp[1];
    }

    // ---- wave-uniform score weights in SGPRs
    float wkq[8][8], csb[8];
    #pragma unroll
    for (int p = 0; p < 8; ++p) {
        csb[p] = uload(ws + 64 + p);
        #pragma unroll
        for (int e = 0; e < 8; ++e) wkq[p][e] = uload(ws + p * 8 + e);
    }

    // ---- phase A: scores + exp, accumulate X_p[e] = sum_s e_p*x[e], S_p = sum e_p
    float Xa[8][8], Sa[8];
    #pragma unroll
    for (int p = 0; p < 8; ++p) {
        Sa[p] = 0.f;
        #pragma unroll
        for (int e = 0; e < 8; ++e) Xa[p][e] = 0.f;
    }
    #pragma unroll
    for (int j = 0; j < 8; ++j) {
        float xv[8] = {lo[j].x, lo[j].y, lo[j].z, lo[j].w,
                       hi[j].x, hi[j].y, hi[j].z, hi[j].w};
        float ep[8];
        #pragma unroll
        for (int p = 0; p < 8; ++p) {
            float sc = csb[p];
            #pragma unroll
            for (int e = 0; e < 8; ++e) sc += wkq[p][e] * xv[e];
            ep[p] = __expf(sc);
            Sa[p] += ep[p];
        }
        #pragma unroll
        for (int p = 0; p < 8; ++p)
            #pragma unroll
            for (int e = 0; e < 8; ++e) Xa[p][e] += ep[p] * xv[e];
    }
    // DPP reduce all 72 accumulators -> lane 63
    #pragma unroll
    for (int p = 0; p < 8; ++p) {
        Sa[p] = wave_sum64(Sa[p]);
        #pragma unroll
        for (int e = 0; e < 8; ++e) Xa[p][e] = wave_sum64(Xa[p][e]);
    }
    if (lane == 63) {
        #pragma unroll
        for (int p = 0; p < 8; ++p) {
            sX[w][64 + p] = Sa[p];
            #pragma unroll
            for (int e = 0; e < 8; ++e) sX[w][p * 8 + e] = Xa[p][e];
        }
    }
    asm volatile("s_waitcnt lgkmcnt(0)" ::: "memory");

    // ---- mid: qcr[f][e] = B2[e] + M0[e].X_f/S_f + M1[e].X_{4+f}/S_{4+f}
    if (lane < 32) {
        const int f = lane >> 3, e = lane & 7;
        const float i0 = 1.f / sX[w][64 + f];
        const float i1 = 1.f / sX[w][64 + 4 + f];
        float d0 = 0.f, d1 = 0.f;
        #pragma unroll
        for (int e2 = 0; e2 < 8; ++e2) {
            d0 += ws[72 + e * 8 + e2] * sX[w][f * 8 + e2];
            d1 += ws[136 + e * 8 + e2] * sX[w][(4 + f) * 8 + e2];
        }
        sQ[w][f * 8 + e] = ws[200 + e] + d0 * i0 + d1 * i1;
    }
    asm volatile("s_waitcnt lgkmcnt(0)" ::: "memory");

    float qc[4][8];
    #pragma unroll
    for (int f = 0; f < 4; ++f)
        #pragma unroll
        for (int e = 0; e < 8; ++e) qc[f][e] = sQ[w][f * 8 + e];

    // ---- phase C: similarity rows (written raw) + fused softmax + final_factors
    float ff[4][8], fz[4];
    #pragma unroll
    for (int f = 0; f < 4; ++f) {
        fz[f] = 0.f;
        #pragma unroll
        for (int e = 0; e < 8; ++e) ff[f][e] = 0.f;
    }
    float* simb = sim_out + (size_t)b * (NFAC * SEQ);
    #pragma unroll
    for (int j = 0; j < 8; ++j) {
        float xv[8] = {lo[j].x, lo[j].y, lo[j].z, lo[j].w,
                       hi[j].x, hi[j].y, hi[j].z, hi[j].w};
        #pragma unroll
        for (int f = 0; f < 4; ++f) {
            float s = 0.f;
            #pragma unroll
            for (int e = 0; e < 8; ++e) s += qc[f][e] * xv[e];
            simb[f * SEQ + lane + 64 * j] = s;
            float ez = __expf(s);
            fz[f] += ez;
            #pragma unroll
            for (int e = 0; e < 8; ++e) ff[f][e] += ez * xv[e];
        }
    }
    #pragma unroll
    for (int f = 0; f < 4; ++f) {
        fz[f] = wave_sum64(fz[f]);
        #pragma unroll
        for (int e = 0; e < 8; ++e) ff[f][e] = wave_sum64(ff[f][e]);
    }
    if (lane == 63) {
        #pragma unroll
        for (int f = 0; f < 4; ++f) {
            float inv = 1.f / fz[f];
            #pragma unroll
            for (int e = 0; e < 8; ++e) sF[w][f * 8 + e] = ff[f][e] * inv;
        }
    }
    asm volatile("s_waitcnt lgkmcnt(0)" ::: "memory");

    // ---- phase D: MLP (lanes 0..15, t = lane)
    if (lane < 16) {
        float h = ws[720 + lane];
        #pragma unroll
        for (int k = 0; k < 32; ++k) h += ws[208 + lane * 32 + k] * sF[w][k];
        h = fmaxf(h, 0.f);
        float v = h * ws[736 + lane];
        v = row16_sum(v);
        if (lane == 15) out[b] = v + ws[752];
    }
}

extern "C" void kernel_launch(void* const* d_in, const int* in_sizes, int n_in,
                              void* d_out, int out_size, void* d_ws, size_t ws_size,
                              hipStream_t stream) {
    const float* x        = (const float*)d_in[0];
    const float* Q        = (const float*)d_in[1];
    const float* sa_w_in  = (const float*)d_in[2];
    const float* sa_b_in  = (const float*)d_in[3];
    const float* sa_w_out = (const float*)d_in[4];
    const float* sa_b_out = (const float*)d_in[5];
    const float* ca_w_in  = (const float*)d_in[6];
    const float* ca_b_in  = (const float*)d_in[7];
    const float* ca_w_out = (const float*)d_in[8];
    const float* ca_b_out = (const float*)d_in[9];
    const float* r_w1     = (const float*)d_in[10];
    const float* r_b1     = (const float*)d_in[11];
    const float* r_w2     = (const float*)d_in[12];
    const float* r_b2     = (const float*)d_in[13];

    float* out = (float*)d_out;
    const int B = in_sizes[0] / (SEQ * EMB);
    float* sim = out + B;            // d_out = [out (B), similarity (B*F*S)]
    float* ws  = (float*)d_ws;       // 753 floats

    precompute_kernel<<<1, 64, 0, stream>>>(Q, sa_w_in, sa_b_in, sa_w_out, sa_b_out,
                                            ca_w_in, ca_b_in, ca_w_out, ca_b_out,
                                            r_w1, r_b1, r_w2, r_b2, ws);
    fused_kernel<<<B / 4, 256, 0, stream>>>(x, ws, out, sim);
}